// Round 13
// baseline (179.891 us; speedup 1.0000x reference)
//
#include <hip/hip_runtime.h>
#include <math.h>

// Shapes (fixed by the problem)
#define Hn 8
#define Sn 1024
#define Dn 64
#define KG 10

// Bias tables: dist in [0,10), energy in [0,5)
#define TN 2048
#define RD 10.25f
#define RE 5.125f

typedef __attribute__((ext_vector_type(8))) short bf16x8;
typedef __attribute__((ext_vector_type(4))) float f32x4;
typedef unsigned short u16;
typedef unsigned int u32;

__device__ inline float bf2f(u16 u) {
    union { u32 i; float f; } v;
    v.i = ((u32)u) << 16;
    return v.f;
}

__device__ inline u16 f2bf(float f) {
    union { float f; u32 i; } v;
    v.f = f;
    u32 i = v.i;
    return (u16)((i + 0x7FFFu + ((i >> 16) & 1u)) >> 16);   // RNE
}

// Fire-and-forget global->LDS DMA, 16 B per lane (R7/R8-proven mechanism:
// no VGPR destination -> RA cannot re-serialize). Readback at lane*16 is
// the identity.
__device__ inline void stage16(const void* g, void* l) {
    __builtin_amdgcn_global_load_lds(
        (const __attribute__((address_space(1))) unsigned int*)g,
        (__attribute__((address_space(3))) unsigned int*)l,
        16, 0, 0);
}

// ---------------------------------------------------------------------------
// RBF (10 gaussians) -> 10x10 MLP (exact gelu) -> scalar, all f32.
// ---------------------------------------------------------------------------
__device__ float bias_eval(float x,
                           const float* __restrict__ mu, const float* __restrict__ sg,
                           const float* __restrict__ bb,
                           const float* __restrict__ W1, const float* __restrict__ b1,
                           const float* __restrict__ W2, const float* __restrict__ b2) {
    const float inv_s2pi = 0.39894228040143267794f;
    float psi[KG];
#pragma unroll
    for (int k = 0; k < KG; k++) {
        float s = sg[k];
        float z = (x + bb[k] - mu[k]) / s;
        psi[k] = __expf(-0.5f * z * z) * (inv_s2pi / s);
    }
    float out = b2[0];
#pragma unroll
    for (int l = 0; l < KG; l++) {
        float a = b1[l];
#pragma unroll
        for (int k = 0; k < KG; k++) a += psi[k] * W1[l * KG + k];
        float g = 0.5f * a * (1.0f + erff(a * 0.70710678118654752440f));
        out += g * W2[l];
    }
    return out;
}

// ---------------------------------------------------------------------------
// Fused prepass (unchanged):
//  ids [0, 2*TN)                 : bias interp tables (bf16 value | bf16 delta)
//  ids [2*TN, 2*TN+262144)       : Q,K f32 -> bf16 (float4 granularity)
//  ids [2*TN+262144, +524288)    : V -> bf16, transposed [h][d][s'] with the
//                                  k-permutation matching the P register order
// ---------------------------------------------------------------------------
#define QK4 262144              // (2*Hn*Sn*Dn)/4
#define VTN 524288              // Hn*Sn*Dn

__global__ __launch_bounds__(256) void prep_kernel(
    const float* __restrict__ Q, const float* __restrict__ K, const float* __restrict__ V,
    const float* __restrict__ muD, const float* __restrict__ sgD, const float* __restrict__ bD,
    const float* __restrict__ muE, const float* __restrict__ sgE, const float* __restrict__ bE,
    const float* __restrict__ W1, const float* __restrict__ b1,
    const float* __restrict__ W2, const float* __restrict__ b2,
    u32* __restrict__ tab, u16* __restrict__ Qb, u16* __restrict__ Kb, u16* __restrict__ VTi)
{
    int id = blockIdx.x * 256 + threadIdx.x;
    if (id < 2 * TN) {
        int which = (id >= TN);
        int idx = id & (TN - 1);
        float h = (which ? RE : RD) / (float)TN;
        float x0 = idx * h;
        float v0, v1;
        if (which) {
            v0 = bias_eval(x0,     muE, sgE, bE, W1, b1, W2, b2);
            v1 = bias_eval(x0 + h, muE, sgE, bE, W1, b1, W2, b2);
        } else {
            v0 = bias_eval(x0,     muD, sgD, bD, W1, b1, W2, b2);
            v1 = bias_eval(x0 + h, muD, sgD, bD, W1, b1, W2, b2);
        }
        tab[id] = (u32)f2bf(v0) | ((u32)f2bf(v1 - v0) << 16);
    } else if (id < 2 * TN + QK4) {
        int i = id - 2 * TN;
        int arr = i >> 17;          // 0 = Q, 1 = K
        i &= (1 << 17) - 1;
        float4 v = ((const float4*)(arr ? K : Q))[i];
        ushort4 o;
        o.x = f2bf(v.x); o.y = f2bf(v.y); o.z = f2bf(v.z); o.w = f2bf(v.w);
        ((ushort4*)(arr ? Kb : Qb))[i] = o;
    } else if (id < 2 * TN + QK4 + VTN) {
        int g = id - (2 * TN + QK4);
        int h = g >> 16;
        int d = (g >> 10) & 63;
        int s = g & 1023;
        int t = s >> 5, q = (s >> 3) & 3, j = s & 7;
        int src_s = (t << 5) + (q << 2) + (j & 3) + ((j >> 2) << 4);
        VTi[g] = f2bf(V[(((size_t)h << 10) + src_s) * Dn + d]);
    }
}

__device__ inline float lerp_tab(const u32* __restrict__ st, float x, float invh) {
    float tf = x * invh;
    int i = (int)tf;
    i = max(0, min(i, TN - 1));
    float fr = tf - (float)i;
    u32 p = st[i];
    return fmaf(bf2f((u16)(p >> 16)), fr, bf2f((u16)p));
}

// ---------------------------------------------------------------------------
// Fused flash attention, R8 structure + T4 counted-vmcnt double-buffer.
// R12 falsified the traffic model (0.71x bytes, same 43 us): every variant
// serialized {issue loads -> vmcnt(0) -> compute} per tile, idling memory
// during compute and ALUs during the drain. Fix: per-wave DOUBLE-buffered
// 14 KB staging; each iteration issues tile t+1's 14 DMAs then waits
// vmcnt(14) -- only tile t's loads (in-order completion), leaving t+1's
// in flight across the whole compute phase. Never drains to 0 mid-loop.
// No barriers (private staging); asm memory clobbers pin iteration order.
// LDS: 16 KB table + 4 waves x 28 KB = 128 KB -> 1 block/CU, 4 waves;
// pipelining replaces TLP. Epilogue overlays sO on the staging buffer.
// ---------------------------------------------------------------------------
#define STW 14336               // staging bytes per buffer per wave

__global__ __launch_bounds__(256) void attn_kernel(
    const u16* __restrict__ Qb, const u16* __restrict__ Kb, const u16* __restrict__ VTi,
    const float* __restrict__ Dm, const float* __restrict__ Em, const int* __restrict__ Mk,
    const u32* __restrict__ gtab, float* __restrict__ out)
{
    __shared__ __align__(16) u32 sTab[2 * TN];          // 16 KB, persistent
    __shared__ __align__(16) char sBuf[4 * 2 * STW];    // 112 KB staging, then sO
    __shared__ float sM[4][16], sL[4][16];

    const int tid = threadIdx.x;
    {   // stage tables: 1024 uint4 over 256 threads
        const uint4* g4 = (const uint4*)gtab;
        uint4* s4 = (uint4*)sTab;
#pragma unroll
        for (int i = 0; i < 4; i++) s4[tid + 256 * i] = g4[tid + 256 * i];
    }
    __syncthreads();

    const int h    = blockIdx.y;
    const int q0   = blockIdx.x * 16;
    const int wave = tid >> 6;
    const int lane = tid & 63;
    const int quad = lane >> 4;
    const int l16  = lane & 15;

    const u16* Qh = Qb  + (size_t)h * Sn * Dn;
    const u16* Kh = Kb  + (size_t)h * Sn * Dn;
    const u16* Vh = VTi + (size_t)h * Dn * Sn;
    const float* Dh = Dm + (size_t)h * Sn * Sn + (size_t)(q0 + l16) * Sn;
    const float* Eh = Em + (size_t)h * Sn * Sn + (size_t)(q0 + l16) * Sn;
    const int*   Mh = Mk + (size_t)h * Sn * Sn + (size_t)(q0 + l16) * Sn;
    const float invhD = (float)TN / RD;
    const float invhE = (float)TN / RE;
    const float scale = 0.08838834764831845f;       // 1/sqrt(2*64)

    // Persistent Q B-fragments: B[n=l16][k=quad*8+j], k = d-dim
    const bf16x8 bQ0 = *(const bf16x8*)(Qh + (q0 + l16) * Dn + quad * 8);
    const bf16x8 bQ1 = *(const bf16x8*)(Qh + (q0 + l16) * Dn + 32 + quad * 8);

    char* stA = sBuf + wave * (2 * STW);        // even tiles
    char* stB = stA + STW;                      // odd tiles

    // stage all 14 chunks of tile tt into buffer b_
#define STAGE(b_, tt) do {                                                    \
        const int k0_ = wave * 256 + (tt) * 32;                               \
        const u16* kr_ = Kh + (size_t)(k0_ + l16) * Dn + quad * 8;            \
        const u16* vr_ = Vh + k0_ + quad * 8 + (size_t)l16 * Sn;              \
        const float* dr_ = Dh + k0_ + quad * 4;                               \
        const float* er_ = Eh + k0_ + quad * 4;                               \
        const int*   mr_ = Mh + k0_ + quad * 4;                               \
        stage16(kr_,                (b_));                                    \
        stage16(kr_ + 32,           (b_) + 1024);                             \
        stage16(kr_ + 16 * Dn,      (b_) + 2048);                             \
        stage16(kr_ + 16 * Dn + 32, (b_) + 3072);                             \
        stage16(vr_,                (b_) + 4096);                             \
        stage16(vr_ + 16 * Sn,      (b_) + 5120);                             \
        stage16(vr_ + 32 * Sn,      (b_) + 6144);                             \
        stage16(vr_ + 48 * Sn,      (b_) + 7168);                             \
        stage16(dr_,                (b_) + 8192);                             \
        stage16(dr_ + 16,           (b_) + 9216);                             \
        stage16(er_,                (b_) + 10240);                            \
        stage16(er_ + 16,           (b_) + 11264);                            \
        stage16(mr_,                (b_) + 12288);                            \
        stage16(mr_ + 16,           (b_) + 13312);                            \
    } while (0)

    f32x4 O0 = {0.f, 0.f, 0.f, 0.f}, O1 = O0, O2 = O0, O3 = O0;
    float m_run = -1e30f, l_run = 0.f;

    STAGE(stA, 0);      // prologue: tile 0 in flight (14 outstanding)

    for (int t = 0; t < 8; t++) {
        char* cur = (t & 1) ? stB : stA;

        if (t < 7) {
            // issue next tile's 14 DMAs into the other buffer (28 outstanding)
            STAGE((t & 1) ? stA : stB, t + 1);
            // wait until only the next tile's 14 remain -> current tile done.
            // In-order completion makes the count exact. Memory stays busy
            // with t+1's loads during the entire compute below.
            asm volatile("s_waitcnt vmcnt(14)" ::: "memory");
        } else {
            asm volatile("s_waitcnt vmcnt(0)" ::: "memory");
        }

        // identity readback: this lane's data at lane*16 in each chunk
        const char* ls = cur + lane * 16;
        const bf16x8 aK00 = *(const bf16x8*)(ls);
        const bf16x8 aK01 = *(const bf16x8*)(ls + 1024);
        const bf16x8 aK10 = *(const bf16x8*)(ls + 2048);
        const bf16x8 aK11 = *(const bf16x8*)(ls + 3072);
        const bf16x8 bV0  = *(const bf16x8*)(ls + 4096);
        const bf16x8 bV1  = *(const bf16x8*)(ls + 5120);
        const bf16x8 bV2  = *(const bf16x8*)(ls + 6144);
        const bf16x8 bV3  = *(const bf16x8*)(ls + 7168);
        const float4 Dv0  = *(const float4*)(ls + 8192);
        const float4 Dv1  = *(const float4*)(ls + 9216);
        const float4 Ev0  = *(const float4*)(ls + 10240);
        const float4 Ev1  = *(const float4*)(ls + 11264);
        const int4   Mv0  = *(const int4*)(ls + 12288);
        const int4   Mv1  = *(const int4*)(ls + 13312);

        // pin this tile's LDS reads before any later iteration's DMA issue
        asm volatile("" ::: "memory");

        f32x4 s0 = {0.f, 0.f, 0.f, 0.f}, s1 = s0;
        s0 = __builtin_amdgcn_mfma_f32_16x16x32_bf16(aK00, bQ0, s0, 0, 0, 0);
        s0 = __builtin_amdgcn_mfma_f32_16x16x32_bf16(aK01, bQ1, s0, 0, 0, 0);
        s1 = __builtin_amdgcn_mfma_f32_16x16x32_bf16(aK10, bQ0, s1, 0, 0, 0);
        s1 = __builtin_amdgcn_mfma_f32_16x16x32_bf16(aK11, bQ1, s1, 0, 0, 0);

        const float dv0[4] = {Dv0.x, Dv0.y, Dv0.z, Dv0.w};
        const float dv1[4] = {Dv1.x, Dv1.y, Dv1.z, Dv1.w};
        const float ev0[4] = {Ev0.x, Ev0.y, Ev0.z, Ev0.w};
        const float ev1[4] = {Ev1.x, Ev1.y, Ev1.z, Ev1.w};
        const int   mv0[4] = {Mv0.x, Mv0.y, Mv0.z, Mv0.w};
        const int   mv1[4] = {Mv1.x, Mv1.y, Mv1.z, Mv1.w};

        float sc0[4], sc1[4];
#pragma unroll
        for (int r = 0; r < 4; r++) {
            float v0 = s0[r] * scale + lerp_tab(sTab, dv0[r], invhD)
                                     + lerp_tab(sTab + TN, ev0[r], invhE);
            v0 = fminf(fmaxf(v0, -80.f), 80.f);
            sc0[r] = (mv0[r] == 0) ? -1e9f : v0;
            float v1 = s1[r] * scale + lerp_tab(sTab, dv1[r], invhD)
                                     + lerp_tab(sTab + TN, ev1[r], invhE);
            v1 = fminf(fmaxf(v1, -80.f), 80.f);
            sc1[r] = (mv1[r] == 0) ? -1e9f : v1;
        }

        // row max: local over 8 values, then across quads (2 shuffles)
        float mloc = fmaxf(fmaxf(fmaxf(sc0[0], sc0[1]), fmaxf(sc0[2], sc0[3])),
                           fmaxf(fmaxf(sc1[0], sc1[1]), fmaxf(sc1[2], sc1[3])));
        mloc = fmaxf(mloc, __shfl_xor(mloc, 16, 64));
        mloc = fmaxf(mloc, __shfl_xor(mloc, 32, 64));

        const float mn = fmaxf(m_run, mloc);
        const float al = __expf(m_run - mn);
        m_run = mn;

        float p0[4], p1[4], ll = 0.f;
#pragma unroll
        for (int r = 0; r < 4; r++) {
            p0[r] = __expf(sc0[r] - mn);
            p1[r] = __expf(sc1[r] - mn);
            ll += p0[r] + p1[r];
        }
        ll += __shfl_xor(ll, 16, 64);
        ll += __shfl_xor(ll, 32, 64);
        l_run = l_run * al + ll;

        // P A-fragment straight from registers (k-order matches permuted V)
        bf16x8 aP;
#pragma unroll
        for (int r = 0; r < 4; r++) {
            aP[r]     = (short)f2bf(p0[r]);
            aP[4 + r] = (short)f2bf(p1[r]);
        }

        // O rescale: alpha for row quad*4+r lives in lane (quad*4+r)
        const float a0 = __shfl(al, quad * 4 + 0, 64);
        const float a1 = __shfl(al, quad * 4 + 1, 64);
        const float a2 = __shfl(al, quad * 4 + 2, 64);
        const float a3 = __shfl(al, quad * 4 + 3, 64);
        O0[0] *= a0; O0[1] *= a1; O0[2] *= a2; O0[3] *= a3;
        O1[0] *= a0; O1[1] *= a1; O1[2] *= a2; O1[3] *= a3;
        O2[0] *= a0; O2[1] *= a1; O2[2] *= a2; O2[3] *= a3;
        O3[0] *= a0; O3[1] *= a1; O3[2] *= a2; O3[3] *= a3;

        O0 = __builtin_amdgcn_mfma_f32_16x16x32_bf16(aP, bV0, O0, 0, 0, 0);
        O1 = __builtin_amdgcn_mfma_f32_16x16x32_bf16(aP, bV1, O1, 0, 0, 0);
        O2 = __builtin_amdgcn_mfma_f32_16x16x32_bf16(aP, bV2, O2, 0, 0, 0);
        O3 = __builtin_amdgcn_mfma_f32_16x16x32_bf16(aP, bV3, O3, 0, 0, 0);
    }
#undef STAGE

    // all waves done with staging before sO overlays it
    __syncthreads();

    float (*sO)[16][68] = (float (*)[16][68])sBuf;  // 17.4 KB < 112 KB
    if (lane < 16) {
        sM[wave][lane] = m_run;
        sL[wave][lane] = l_run;
    }
#pragma unroll
    for (int r = 0; r < 4; r++) {
        sO[wave][quad * 4 + r][ 0 + l16] = O0[r];
        sO[wave][quad * 4 + r][16 + l16] = O1[r];
        sO[wave][quad * 4 + r][32 + l16] = O2[r];
        sO[wave][quad * 4 + r][48 + l16] = O3[r];
    }
    __syncthreads();

    const int row = tid >> 4;
    const int c4  = (tid & 15) * 4;
    float mg = sM[0][row];
#pragma unroll
    for (int w = 1; w < 4; w++) mg = fmaxf(mg, sM[w][row]);
    float fac[4], lg = 0.f;
#pragma unroll
    for (int w = 0; w < 4; w++) {
        fac[w] = __expf(sM[w][row] - mg);
        lg += sL[w][row] * fac[w];
    }
    const float inv = 1.0f / lg;

    float acc[4];
#pragma unroll
    for (int c = 0; c < 4; c++) {
        acc[c] = 0.f;
#pragma unroll
        for (int w = 0; w < 4; w++) acc[c] += sO[w][row][c4 + c] * fac[w];
        acc[c] *= inv;
    }
    float4 ov = {acc[0], acc[1], acc[2], acc[3]};
    *(float4*)(out + ((size_t)(h * Sn + q0 + row)) * Dn + c4) = ov;
}

// ---------------------------------------------------------------------------
extern "C" void kernel_launch(void* const* d_in, const int* in_sizes, int n_in,
                              void* d_out, int out_size, void* d_ws, size_t ws_size,
                              hipStream_t stream) {
    const float* Q    = (const float*)d_in[0];
    const float* K    = (const float*)d_in[1];
    const float* V    = (const float*)d_in[2];
    const float* Dm   = (const float*)d_in[3];
    const float* Em   = (const float*)d_in[4];
    const int*   Mask = (const int*)d_in[5];
    const float* muD  = (const float*)d_in[6];
    const float* sgD  = (const float*)d_in[7];
    const float* bD   = (const float*)d_in[8];
    const float* muE  = (const float*)d_in[9];
    const float* sgE  = (const float*)d_in[10];
    const float* bE   = (const float*)d_in[11];
    const float* W1   = (const float*)d_in[12];
    const float* b1   = (const float*)d_in[13];
    const float* W2   = (const float*)d_in[14];
    const float* b2   = (const float*)d_in[15];

    // ws layout: tab 16 KB | Qb 1 MB | Kb 1 MB | VTi 1 MB  (~3.1 MB total)
    u32* tab = (u32*)d_ws;
    u16* Qb  = (u16*)((char*)d_ws + 2 * TN * 4);
    u16* Kb  = Qb + (size_t)Hn * Sn * Dn;
    u16* VTi = Kb + (size_t)Hn * Sn * Dn;

    const int prep_threads = 2 * TN + QK4 + VTN;           // 790528
    prep_kernel<<<prep_threads / 256, 256, 0, stream>>>(
        Q, K, V, muD, sgD, bD, muE, sgE, bE, W1, b1, W2, b2,
        tab, Qb, Kb, VTi);

    dim3 grid(Sn / 16, Hn);
    attn_kernel<<<grid, 256, 0, stream>>>(Qb, Kb, VTi, Dm, Em, Mask, tab,
                                          (float*)d_out);
}

// Round 14
// 173.094 us; speedup vs baseline: 1.0393x; 1.0393x over previous
//
#include <hip/hip_runtime.h>
#include <math.h>

// Shapes (fixed by the problem)
#define Hn 8
#define Sn 1024
#define Dn 64
#define KG 10

// Bias tables: dist in [0,10), energy in [0,5)
#define TN 2048
#define RD 10.25f
#define RE 5.125f

typedef __attribute__((ext_vector_type(8))) short bf16x8;
typedef __attribute__((ext_vector_type(4))) float f32x4;
typedef unsigned short u16;
typedef unsigned int u32;

__device__ inline float bf2f(u16 u) {
    union { u32 i; float f; } v;
    v.i = ((u32)u) << 16;
    return v.f;
}

__device__ inline u16 f2bf(float f) {
    union { float f; u32 i; } v;
    v.f = f;
    u32 i = v.i;
    return (u16)((i + 0x7FFFu + ((i >> 16) & 1u)) >> 16);   // RNE
}

// Fire-and-forget global->LDS DMA, 16 B per lane. No VGPR destination ->
// the register allocator cannot re-serialize these (R7/R8 confirmed: this is
// the one clustering mechanism hipcc does not defeat). LDS dest is
// wave-uniform base + lane*16; global src is per-lane; readback at lane*16
// is the identity for every chunk (K, V, D, E, M alike).
__device__ inline void stage16(const void* g, void* l) {
    __builtin_amdgcn_global_load_lds(
        (const __attribute__((address_space(1))) unsigned int*)g,
        (__attribute__((address_space(3))) unsigned int*)l,
        16, 0, 0);
}

// ---------------------------------------------------------------------------
// RBF (10 gaussians) -> 10x10 MLP (exact gelu) -> scalar, all f32.
// ---------------------------------------------------------------------------
__device__ float bias_eval(float x,
                           const float* __restrict__ mu, const float* __restrict__ sg,
                           const float* __restrict__ bb,
                           const float* __restrict__ W1, const float* __restrict__ b1,
                           const float* __restrict__ W2, const float* __restrict__ b2) {
    const float inv_s2pi = 0.39894228040143267794f;
    float psi[KG];
#pragma unroll
    for (int k = 0; k < KG; k++) {
        float s = sg[k];
        float z = (x + bb[k] - mu[k]) / s;
        psi[k] = __expf(-0.5f * z * z) * (inv_s2pi / s);
    }
    float out = b2[0];
#pragma unroll
    for (int l = 0; l < KG; l++) {
        float a = b1[l];
#pragma unroll
        for (int k = 0; k < KG; k++) a += psi[k] * W1[l * KG + k];
        float g = 0.5f * a * (1.0f + erff(a * 0.70710678118654752440f));
        out += g * W2[l];
    }
    return out;
}

// ---------------------------------------------------------------------------
// Fused prepass:
//  ids [0, 2*TN)                 : bias interp tables (bf16 value | bf16 delta)
//  ids [2*TN, 2*TN+262144)       : Q,K f32 -> bf16 (float4 granularity)
//  ids [2*TN+262144, +524288)    : V -> bf16, transposed [h][d][s'] with the
//                                  k-permutation matching the P register order
// ---------------------------------------------------------------------------
#define QK4 262144              // (2*Hn*Sn*Dn)/4
#define VTN 524288              // Hn*Sn*Dn

__global__ __launch_bounds__(256) void prep_kernel(
    const float* __restrict__ Q, const float* __restrict__ K, const float* __restrict__ V,
    const float* __restrict__ muD, const float* __restrict__ sgD, const float* __restrict__ bD,
    const float* __restrict__ muE, const float* __restrict__ sgE, const float* __restrict__ bE,
    const float* __restrict__ W1, const float* __restrict__ b1,
    const float* __restrict__ W2, const float* __restrict__ b2,
    u32* __restrict__ tab, u16* __restrict__ Qb, u16* __restrict__ Kb, u16* __restrict__ VTi)
{
    int id = blockIdx.x * 256 + threadIdx.x;
    if (id < 2 * TN) {
        int which = (id >= TN);
        int idx = id & (TN - 1);
        float h = (which ? RE : RD) / (float)TN;
        float x0 = idx * h;
        float v0, v1;
        if (which) {
            v0 = bias_eval(x0,     muE, sgE, bE, W1, b1, W2, b2);
            v1 = bias_eval(x0 + h, muE, sgE, bE, W1, b1, W2, b2);
        } else {
            v0 = bias_eval(x0,     muD, sgD, bD, W1, b1, W2, b2);
            v1 = bias_eval(x0 + h, muD, sgD, bD, W1, b1, W2, b2);
        }
        tab[id] = (u32)f2bf(v0) | ((u32)f2bf(v1 - v0) << 16);
    } else if (id < 2 * TN + QK4) {
        int i = id - 2 * TN;
        int arr = i >> 17;          // 0 = Q, 1 = K
        i &= (1 << 17) - 1;
        float4 v = ((const float4*)(arr ? K : Q))[i];
        ushort4 o;
        o.x = f2bf(v.x); o.y = f2bf(v.y); o.z = f2bf(v.z); o.w = f2bf(v.w);
        ((ushort4*)(arr ? Kb : Qb))[i] = o;
    } else if (id < 2 * TN + QK4 + VTN) {
        int g = id - (2 * TN + QK4);
        int h = g >> 16;
        int d = (g >> 10) & 63;
        int s = g & 1023;
        int t = s >> 5, q = (s >> 3) & 3, j = s & 7;
        int src_s = (t << 5) + (q << 2) + (j & 3) + ((j >> 2) << 4);
        VTi[g] = f2bf(V[(((size_t)h << 10) + src_s) * Dn + d]);
    }
}

__device__ inline float lerp_tab(const u32* __restrict__ st, float x, float invh) {
    float tf = x * invh;
    int i = (int)tf;
    i = max(0, min(i, TN - 1));
    float fr = tf - (float)i;
    u32 p = st[i];
    return fmaf(bf2f((u16)(p >> 16)), fr, bf2f((u16)p));
}

// ---------------------------------------------------------------------------
// Fully fused flash attention, S^T formulation. Per tile ALL 14 input chunks
// (4 K + 4 V + 2 Dm + 2 Em + 2 Mask, 16 B/lane each) are staged via
// global_load_lds DMA into a private 14 KB region per wave -- they issue
// back-to-back (R7-verified mechanism), one s_waitcnt vmcnt(0) per tile pays
// ONE memory latency instead of 14. No Cb intermediate, D/E/M streamed
// exactly once from HBM, bias lerped from the 16 KB LDS table.
// LDS: 16 KB table + 56 KB staging + eps = 74 KB -> 2 blocks/CU, 8 waves/CU.
// Epilogue overlays sO on the staging buffer after a barrier.
// This is the session's empirical best (R8: 173.0 us total, attn 43.4 us);
// R9-R13 explored shared staging / occupancy / counted-vmcnt and all landed
// at >= this time. Reverted per the R12 pre-commitment.
// ---------------------------------------------------------------------------
#define STW 14336               // staging bytes per wave

__global__ __launch_bounds__(256) void attn_kernel(
    const u16* __restrict__ Qb, const u16* __restrict__ Kb, const u16* __restrict__ VTi,
    const float* __restrict__ Dm, const float* __restrict__ Em, const int* __restrict__ Mk,
    const u32* __restrict__ gtab, float* __restrict__ out)
{
    __shared__ __align__(16) u32 sTab[2 * TN];      // 16 KB, persistent
    __shared__ __align__(16) char sBuf[4 * STW];    // 56 KB staging, then sO
    __shared__ float sM[4][16], sL[4][16];

    const int tid = threadIdx.x;
    {   // stage tables: 1024 uint4 over 256 threads
        const uint4* g4 = (const uint4*)gtab;
        uint4* s4 = (uint4*)sTab;
#pragma unroll
        for (int i = 0; i < 4; i++) s4[tid + 256 * i] = g4[tid + 256 * i];
    }
    __syncthreads();

    const int h    = blockIdx.y;
    const int q0   = blockIdx.x * 16;
    const int wave = tid >> 6;
    const int lane = tid & 63;
    const int quad = lane >> 4;
    const int l16  = lane & 15;

    const u16* Qh = Qb  + (size_t)h * Sn * Dn;
    const u16* Kh = Kb  + (size_t)h * Sn * Dn;
    const u16* Vh = VTi + (size_t)h * Dn * Sn;
    const float* Dh = Dm + (size_t)h * Sn * Sn + (size_t)(q0 + l16) * Sn;
    const float* Eh = Em + (size_t)h * Sn * Sn + (size_t)(q0 + l16) * Sn;
    const int*   Mh = Mk + (size_t)h * Sn * Sn + (size_t)(q0 + l16) * Sn;
    const float invhD = (float)TN / RD;
    const float invhE = (float)TN / RE;
    const float scale = 0.08838834764831845f;       // 1/sqrt(2*64)

    // Persistent Q B-fragments: B[n=l16][k=quad*8+j], k = d-dim
    const bf16x8 bQ0 = *(const bf16x8*)(Qh + (q0 + l16) * Dn + quad * 8);
    const bf16x8 bQ1 = *(const bf16x8*)(Qh + (q0 + l16) * Dn + 32 + quad * 8);

    char* st = sBuf + wave * STW;       // wave-private staging (14 x 1 KB)

    f32x4 O0 = {0.f, 0.f, 0.f, 0.f}, O1 = O0, O2 = O0, O3 = O0;
    float m_run = -1e30f, l_run = 0.f;

    for (int t = 0; t < 8; t++) {
        const int k0 = wave * 256 + t * 32;

        // ---- stage all 14 chunks: fire-and-forget DMA, no VGPR dests ----
        const u16* kr = Kh + (size_t)(k0 + l16) * Dn + quad * 8;
        const u16* vr = Vh + k0 + quad * 8 + (size_t)l16 * Sn;
        const float* dr = Dh + k0 + quad * 4;
        const float* er = Eh + k0 + quad * 4;
        const int*   mr = Mh + k0 + quad * 4;
        stage16(kr,                st);
        stage16(kr + 32,           st + 1024);
        stage16(kr + 16 * Dn,      st + 2048);
        stage16(kr + 16 * Dn + 32, st + 3072);
        stage16(vr,                st + 4096);
        stage16(vr + 16 * Sn,      st + 5120);
        stage16(vr + 32 * Sn,      st + 6144);
        stage16(vr + 48 * Sn,      st + 7168);
        stage16(dr,                st + 8192);
        stage16(dr + 16,           st + 9216);
        stage16(er,                st + 10240);
        stage16(er + 16,           st + 11264);
        stage16(mr,                st + 12288);
        stage16(mr + 16,           st + 13312);

        asm volatile("s_waitcnt vmcnt(0)" ::: "memory");

        // identity readback: this lane's data at lane*16 in each chunk
        const char* ls = st + lane * 16;
        const bf16x8 aK00 = *(const bf16x8*)(ls);
        const bf16x8 aK01 = *(const bf16x8*)(ls + 1024);
        const bf16x8 aK10 = *(const bf16x8*)(ls + 2048);
        const bf16x8 aK11 = *(const bf16x8*)(ls + 3072);
        const bf16x8 bV0  = *(const bf16x8*)(ls + 4096);
        const bf16x8 bV1  = *(const bf16x8*)(ls + 5120);
        const bf16x8 bV2  = *(const bf16x8*)(ls + 6144);
        const bf16x8 bV3  = *(const bf16x8*)(ls + 7168);
        const float4 Dv0  = *(const float4*)(ls + 8192);
        const float4 Dv1  = *(const float4*)(ls + 9216);
        const float4 Ev0  = *(const float4*)(ls + 10240);
        const float4 Ev1  = *(const float4*)(ls + 11264);
        const int4   Mv0  = *(const int4*)(ls + 12288);
        const int4   Mv1  = *(const int4*)(ls + 13312);

        // pin the LDS reads above before any later DMA can overwrite them
        asm volatile("" ::: "memory");

        f32x4 s0 = {0.f, 0.f, 0.f, 0.f}, s1 = s0;
        s0 = __builtin_amdgcn_mfma_f32_16x16x32_bf16(aK00, bQ0, s0, 0, 0, 0);
        s0 = __builtin_amdgcn_mfma_f32_16x16x32_bf16(aK01, bQ1, s0, 0, 0, 0);
        s1 = __builtin_amdgcn_mfma_f32_16x16x32_bf16(aK10, bQ0, s1, 0, 0, 0);
        s1 = __builtin_amdgcn_mfma_f32_16x16x32_bf16(aK11, bQ1, s1, 0, 0, 0);

        const float dv0[4] = {Dv0.x, Dv0.y, Dv0.z, Dv0.w};
        const float dv1[4] = {Dv1.x, Dv1.y, Dv1.z, Dv1.w};
        const float ev0[4] = {Ev0.x, Ev0.y, Ev0.z, Ev0.w};
        const float ev1[4] = {Ev1.x, Ev1.y, Ev1.z, Ev1.w};
        const int   mv0[4] = {Mv0.x, Mv0.y, Mv0.z, Mv0.w};
        const int   mv1[4] = {Mv1.x, Mv1.y, Mv1.z, Mv1.w};

        float sc0[4], sc1[4];
#pragma unroll
        for (int r = 0; r < 4; r++) {
            float v0 = s0[r] * scale + lerp_tab(sTab, dv0[r], invhD)
                                     + lerp_tab(sTab + TN, ev0[r], invhE);
            v0 = fminf(fmaxf(v0, -80.f), 80.f);
            sc0[r] = (mv0[r] == 0) ? -1e9f : v0;
            float v1 = s1[r] * scale + lerp_tab(sTab, dv1[r], invhD)
                                     + lerp_tab(sTab + TN, ev1[r], invhE);
            v1 = fminf(fmaxf(v1, -80.f), 80.f);
            sc1[r] = (mv1[r] == 0) ? -1e9f : v1;
        }

        // row max: local over 8 values, then across quads (2 shuffles)
        float mloc = fmaxf(fmaxf(fmaxf(sc0[0], sc0[1]), fmaxf(sc0[2], sc0[3])),
                           fmaxf(fmaxf(sc1[0], sc1[1]), fmaxf(sc1[2], sc1[3])));
        mloc = fmaxf(mloc, __shfl_xor(mloc, 16, 64));
        mloc = fmaxf(mloc, __shfl_xor(mloc, 32, 64));

        const float mn = fmaxf(m_run, mloc);
        const float al = __expf(m_run - mn);
        m_run = mn;

        float p0[4], p1[4], ll = 0.f;
#pragma unroll
        for (int r = 0; r < 4; r++) {
            p0[r] = __expf(sc0[r] - mn);
            p1[r] = __expf(sc1[r] - mn);
            ll += p0[r] + p1[r];
        }
        ll += __shfl_xor(ll, 16, 64);
        ll += __shfl_xor(ll, 32, 64);
        l_run = l_run * al + ll;

        // P A-fragment straight from registers (k-order matches permuted V)
        bf16x8 aP;
#pragma unroll
        for (int r = 0; r < 4; r++) {
            aP[r]     = (short)f2bf(p0[r]);
            aP[4 + r] = (short)f2bf(p1[r]);
        }

        // O rescale: alpha for row quad*4+r lives in lane (quad*4+r)
        const float a0 = __shfl(al, quad * 4 + 0, 64);
        const float a1 = __shfl(al, quad * 4 + 1, 64);
        const float a2 = __shfl(al, quad * 4 + 2, 64);
        const float a3 = __shfl(al, quad * 4 + 3, 64);
        O0[0] *= a0; O0[1] *= a1; O0[2] *= a2; O0[3] *= a3;
        O1[0] *= a0; O1[1] *= a1; O1[2] *= a2; O1[3] *= a3;
        O2[0] *= a0; O2[1] *= a1; O2[2] *= a2; O2[3] *= a3;
        O3[0] *= a0; O3[1] *= a1; O3[2] *= a2; O3[3] *= a3;

        O0 = __builtin_amdgcn_mfma_f32_16x16x32_bf16(aP, bV0, O0, 0, 0, 0);
        O1 = __builtin_amdgcn_mfma_f32_16x16x32_bf16(aP, bV1, O1, 0, 0, 0);
        O2 = __builtin_amdgcn_mfma_f32_16x16x32_bf16(aP, bV2, O2, 0, 0, 0);
        O3 = __builtin_amdgcn_mfma_f32_16x16x32_bf16(aP, bV3, O3, 0, 0, 0);
    }

    // all waves done with staging before sO overlays it
    __syncthreads();

    float (*sO)[16][68] = (float (*)[16][68])sBuf;  // 17.4 KB < 56 KB
    if (lane < 16) {
        sM[wave][lane] = m_run;
        sL[wave][lane] = l_run;
    }
#pragma unroll
    for (int r = 0; r < 4; r++) {
        sO[wave][quad * 4 + r][ 0 + l16] = O0[r];
        sO[wave][quad * 4 + r][16 + l16] = O1[r];
        sO[wave][quad * 4 + r][32 + l16] = O2[r];
        sO[wave][quad * 4 + r][48 + l16] = O3[r];
    }
    __syncthreads();

    const int row = tid >> 4;
    const int c4  = (tid & 15) * 4;
    float mg = sM[0][row];
#pragma unroll
    for (int w = 1; w < 4; w++) mg = fmaxf(mg, sM[w][row]);
    float fac[4], lg = 0.f;
#pragma unroll
    for (int w = 0; w < 4; w++) {
        fac[w] = __expf(sM[w][row] - mg);
        lg += sL[w][row] * fac[w];
    }
    const float inv = 1.0f / lg;

    float acc[4];
#pragma unroll
    for (int c = 0; c < 4; c++) {
        acc[c] = 0.f;
#pragma unroll
        for (int w = 0; w < 4; w++) acc[c] += sO[w][row][c4 + c] * fac[w];
        acc[c] *= inv;
    }
    float4 ov = {acc[0], acc[1], acc[2], acc[3]};
    *(float4*)(out + ((size_t)(h * Sn + q0 + row)) * Dn + c4) = ov;
}

// ---------------------------------------------------------------------------
extern "C" void kernel_launch(void* const* d_in, const int* in_sizes, int n_in,
                              void* d_out, int out_size, void* d_ws, size_t ws_size,
                              hipStream_t stream) {
    const float* Q    = (const float*)d_in[0];
    const float* K    = (const float*)d_in[1];
    const float* V    = (const float*)d_in[2];
    const float* Dm   = (const float*)d_in[3];
    const float* Em   = (const float*)d_in[4];
    const int*   Mask = (const int*)d_in[5];
    const float* muD  = (const float*)d_in[6];
    const float* sgD  = (const float*)d_in[7];
    const float* bD   = (const float*)d_in[8];
    const float* muE  = (const float*)d_in[9];
    const float* sgE  = (const float*)d_in[10];
    const float* bE   = (const float*)d_in[11];
    const float* W1   = (const float*)d_in[12];
    const float* b1   = (const float*)d_in[13];
    const float* W2   = (const float*)d_in[14];
    const float* b2   = (const float*)d_in[15];

    // ws layout: tab 16 KB | Qb 1 MB | Kb 1 MB | VTi 1 MB  (~3.1 MB total)
    u32* tab = (u32*)d_ws;
    u16* Qb  = (u16*)((char*)d_ws + 2 * TN * 4);
    u16* Kb  = Qb + (size_t)Hn * Sn * Dn;
    u16* VTi = Kb + (size_t)Hn * Sn * Dn;

    const int prep_threads = 2 * TN + QK4 + VTN;           // 790528
    prep_kernel<<<prep_threads / 256, 256, 0, stream>>>(
        Q, K, V, muD, sgD, bD, muE, sgE, bE, W1, b1, W2, b2,
        tab, Qb, Kb, VTi);

    dim3 grid(Sn / 16, Hn);
    attn_kernel<<<grid, 256, 0, stream>>>(Qb, Kb, VTi, Dm, Em, Mask, tab,
                                          (float*)d_out);
}